// Round 13
// baseline (110917.212 us; speedup 1.0000x reference)
//
#include <hip/hip_runtime.h>
#include <math.h>

#define NLS    4096   // 512 nodes * 8 stalk dims (= 64*64, so 64-tiles tile it exactly)
#define NNODE  512
#define SDIM   8
#define KNN_K  5
#define MAXNBR 128
#define DIN    768
#define NB     32     // panel width
#define GMEGA  448    // WGs per z-slice (896 total <= 1024 capacity @ 4 WG/CU)

#define AGLD(p)    __hip_atomic_load((p), __ATOMIC_RELAXED, __HIP_MEMORY_SCOPE_AGENT)
#define AGST(p, v) __hip_atomic_store((p), (v), __ATOMIC_RELAXED, __HIP_MEMORY_SCOPE_AGENT)

struct Ptrs {
  float* X;      // [2][NNODE][SDIM]
  int*   nn;     // [2][NNODE][KNN_K]
  int*   nbr;    // [2][NNODE][MAXNBR]
  int*   cnt;    // [2][NNODE]
  float* y;      // [2][2][NLS]   y accumulator, double-buffered by column parity (zeroed)
  float* acol;   // [2][NLS]      corrected column k (sc1)
  float* vtw;    // [2][NLS]      v^T y accumulators (zeroed, single-use)
  float* xn2;    // [2][NLS]      next-column xnorm2 accumulators (zeroed, single-use)
  float* darr;   // [2][NLS]
  float* ebuf;   // [2][NLS]
  float* e2;     // [2][NLS]
  float* bounds; // [2][2]
  float* eigs;   // [2][NLS]
  float* Vt;     // [2][NB][NLS]
  float* Wt;     // [2][NB][NLS]
  float* c1;     // [2][NLS][NB]  per-column slots (zeroed, single-use)
  float* c2;     // [2][NLS][NB]
  int*   barmem; // [2][2048]     leaves 0..511, root 512, release 768
  float* A0;
  float* A1;
};

__device__ __forceinline__ float* matA(const Ptrs& p, int cloud) {
  return cloud == 0 ? p.A0 : p.A1;
}

// Two-level tree barrier with generation counting (proven R6-R12).
__device__ __forceinline__ void tbar(int* bm, int act, int bid, int& gen,
                                     int& leafbase, int& rootbase, bool fence) {
  __syncthreads();
  if (threadIdx.x == 0) {
    gen += 1;
    int perleaf = act >> 5;                       // act is a multiple of 32
    if (fence) __threadfence();
    else       __builtin_amdgcn_s_waitcnt(0);
    int* leaf = bm + ((bid & 31) << 4);
    int old = __hip_atomic_fetch_add(leaf, 1, __ATOMIC_RELAXED, __HIP_MEMORY_SCOPE_AGENT);
    if (old == leafbase + perleaf - 1) {
      int ro = __hip_atomic_fetch_add(bm + 512, 1, __ATOMIC_RELAXED, __HIP_MEMORY_SCOPE_AGENT);
      if (ro == rootbase + 31) AGST(bm + 768, gen);
    }
    leafbase += perleaf;
    rootbase += 32;
    while (AGLD(bm + 768) < gen) __builtin_amdgcn_s_sleep(8);
    if (fence) __threadfence();
  }
  __syncthreads();
}

// ---------------- zero helper ----------------
__global__ void zero_kernel(float* ptr, long n) {
  long i = (long)blockIdx.x * 256 + threadIdx.x;
  if (i < n) ptr[i] = 0.f;
}

// ---------------- projection: X = emb @ W^T ----------------
__global__ void proj_kernel(Ptrs p, const float* q, const float* pe,
                            const float* ne, const float* W) {
  int idx = blockIdx.x * 256 + threadIdx.x;
  if (idx >= 2 * NNODE * SDIM) return;
  int cloud = idx >> 12;
  int rem   = idx & 4095;
  int node  = rem >> 3, t = rem & 7;
  const float* src = (node < 256) ? (q + (size_t)node * DIN)
                                  : ((cloud == 0 ? pe : ne) + (size_t)(node - 256) * DIN);
  const float* wr = W + (size_t)t * DIN;
  float acc = 0.f;
  for (int i = 0; i < DIN; ++i) acc += src[i] * wr[i];
  p.X[(cloud * NNODE + node) * SDIM + t] = acc;
}

// ---------------- KNN ----------------
__global__ void knn_kernel(Ptrs p) {
  int i = blockIdx.x, cloud = blockIdx.z;
  int lane = threadIdx.x;
  __shared__ float d2s[NNODE];
  const float* X = p.X + cloud * NNODE * SDIM;
  float xi[SDIM];
  for (int t = 0; t < SDIM; ++t) xi[t] = X[i * SDIM + t];
  for (int j = lane; j < NNODE; j += 64) {
    float s = 0.f;
    for (int t = 0; t < SDIM; ++t) { float d = xi[t] - X[j * SDIM + t]; s += d * d; }
    d2s[j] = (j == i) ? 3.4e38f : s;
  }
  __syncthreads();
  for (int r = 0; r < KNN_K; ++r) {
    float bv = 3.39e38f; int bi = NNODE;
    for (int j = lane; j < NNODE; j += 64) {
      float val = d2s[j];
      if (val < bv || (val == bv && j < bi)) { bv = val; bi = j; }
    }
    for (int o = 32; o > 0; o >>= 1) {
      float ov = __shfl_down(bv, o); int oi = __shfl_down(bi, o);
      if (ov < bv || (ov == bv && oi < bi)) { bv = ov; bi = oi; }
    }
    if (lane == 0) {
      p.nn[(cloud * NNODE + i) * KNN_K + r] = bi;
      d2s[bi] = 3.4e38f;
    }
    __syncthreads();
  }
}

// ---------------- symmetrized adjacency ----------------
__global__ void adj_kernel(Ptrs p) {
  int idx = blockIdx.x * 256 + threadIdx.x;
  if (idx >= 2 * NNODE) return;
  int cloud = idx >> 9, i = idx & 511;
  const int* nn = p.nn + cloud * NNODE * KNN_K;
  int c = 0;
  for (int j = 0; j < NNODE; ++j) {
    if (j == i) continue;
    bool e = false;
    for (int r = 0; r < KNN_K; ++r)
      if (nn[i * KNN_K + r] == j || nn[j * KNN_K + r] == i) e = true;
    if (e) { if (c < MAXNBR) p.nbr[(cloud * NNODE + i) * MAXNBR + c] = j; ++c; }
  }
  p.cnt[cloud * NNODE + i] = (c > MAXNBR ? MAXNBR : c);
}

// ---------------- dense assembly of L (full square) ----------------
__global__ void assemble_kernel(Ptrs p, int cloud0) {
  int i = blockIdx.x;
  int cloud = cloud0 + blockIdx.z;
  float* A = matA(p, cloud);
  const float* X = p.X + cloud * NNODE * SDIM;
  const int* nbr = p.nbr + (cloud * NNODE + i) * MAXNBR;
  int cnt = p.cnt[cloud * NNODE + i];
  int tid = threadIdx.x;

  for (int idx = tid; idx < SDIM * NLS; idx += 256) {
    int t = idx >> 12;
    int c = idx & 4095;
    A[(size_t)(i * SDIM + t) * NLS + c] = 0.f;
  }
  __shared__ float diag[64];
  __shared__ float xi[SDIM];
  if (tid < SDIM) xi[tid] = X[i * SDIM + tid];
  if (tid < 64)   diag[tid] = 0.f;
  __syncthreads();

  for (int s = 0; s < cnt; ++s) {
    int j = nbr[s];
    float d[SDIM], ss = 0.f;
    for (int t = 0; t < SDIM; ++t) { d[t] = X[j * SDIM + t] - xi[t]; ss += d[t] * d[t]; }
    float dn = sqrtf(ss) + 1e-12f;
    float alpha = dn < 1.f ? dn : 1.f;
    float inv = 1.f / dn;
    if (tid < 64) {
      int t = tid >> 3, t2 = tid & 7;
      float ut = d[t] * inv, ut2 = d[t2] * inv;
      A[(size_t)(i * SDIM + t) * NLS + j * SDIM + t2] =
          alpha * ut * ut2 - (t == t2 ? 1.f : 0.f);
      if (j < i) {
        float beta = 2.f * alpha - alpha * alpha;
        diag[tid] += beta * ut * ut2;
      }
    }
  }
  __syncthreads();
  if (tid < 64) {
    int t = tid >> 3, t2 = tid & 7;
    A[(size_t)(i * SDIM + t) * NLS + i * SDIM + t2] =
        (t == t2 ? (float)cnt : 0.f) - diag[tid];
  }
}

// ---------------- persistent mega-kernel: full blocked tridiagonalization ----
// R12 structure; phase-1 per-tile sync count 3->2, direct per-wave y atomics.
__global__ __launch_bounds__(256, 4) void mega_kernel(Ptrs p, int cloud0) {
  const int cloud = cloud0 + blockIdx.z;
  const int bid = blockIdx.x;
  float* A  = matA(p, cloud);
  float* Vt = p.Vt + (size_t)cloud * NB * NLS;
  float* Wt = p.Wt + (size_t)cloud * NB * NLS;
  float* acol = p.acol + (size_t)cloud * NLS;
  float* c1g = p.c1 + (size_t)cloud * NLS * NB;
  float* c2g = p.c2 + (size_t)cloud * NLS * NB;
  float* xn2g = p.xn2 + (size_t)cloud * NLS;
  int* bm = p.barmem + (size_t)cloud * 2048;
  int gen = 0, leafbase = 0, rootbase = 0;
  const int tid = threadIdx.x, lane = tid & 63, wv = tid >> 6;

  __shared__ __align__(16) union {
    struct {
      float v[NLS + 4];           // 16.4 KB  (live through phase 1+2)
      float tile[64][65];         // 16.6 KB  (per-tile staging, pad 65: conflict-free)
    } p1;
    struct { float Vr[NB][64], Wr[NB][64], Vc[NB][64], Wc[NB][64]; } t;  // 32 KB
  } sh;
  __shared__ float c1s[NB], c2s[NB], vks[NB], wks[NB];
  __shared__ float red4[4], rda[4], rdb[4];

  for (int k0 = 0; k0 + NB <= NLS - 64; k0 += NB) {
    int act = (NLS - k0) >> 3;
    act = (act + 31) & ~31;
    if (act < 64)    act = 64;
    if (act > GMEGA) act = GMEGA;
    if (bid >= act) return;

    for (int jj = 0; jj < NB; ++jj) {
      const int k = k0 + jj, s = k + 1;
      const int vbase = s & ~63;          // 64-aligned tile/v origin
      const int vn = NLS - vbase;
      float* yv    = p.y + ((size_t)cloud * 2 + (k & 1)) * NLS;
      float* ynext = p.y + ((size_t)cloud * 2 + ((k + 1) & 1)) * NLS;
      const int nt = vn >> 6;             // tiles exactly cover [vbase, NLS)
      const int T = (nt * (nt + 1)) >> 1;

      // tile index decode + register prefetch helpers
      auto tileIJ = [&](int item, int& R0, int& C0, bool& dg) {
        int I = (int)((sqrtf(8.f * (float)item + 1.f) - 1.f) * 0.5f);
        while (((I + 1) * (I + 2)) / 2 <= item) ++I;
        while ((I * (I + 1)) / 2 > item) --I;
        int J = item - (I * (I + 1)) / 2;
        R0 = vbase + (I << 6); C0 = vbase + (J << 6); dg = (I == J);
      };
      float4 rg0, rg1, rg2, rg3;
      auto loadRegs = [&](int R0, int C0) {
        const int i0 = tid >> 4, q0 = (tid & 15) << 2;
        const float* basep = A + (size_t)R0 * NLS + C0;
        rg0 = *(const float4*)(basep + (size_t)(i0     ) * NLS + q0);
        rg1 = *(const float4*)(basep + (size_t)(i0 + 16) * NLS + q0);
        rg2 = *(const float4*)(basep + (size_t)(i0 + 32) * NLS + q0);
        rg3 = *(const float4*)(basep + (size_t)(i0 + 48) * NLS + q0);
      };

      // hoisted first-tile prefetch: overlaps the column preamble
      int R0c = 0, C0c = 0; bool dgc = false;
      if (bid < T) { tileIJ(bid, R0c, C0c, dgc); loadRegs(R0c, C0c); }

      // ---- column preamble: Householder scalars + stage v (scaled) ----
      float tau, scale;
      if (jj == 0) {
        const float* src = A + (size_t)k * NLS;   // stale row k
        float xp = 0.f;
        for (int i = tid; i < vn; i += 256) {
          int c = vbase + i;
          float a = (c < s) ? 0.f : AGLD((float*)&src[c]);
          sh.p1.v[i] = a;
          if (c > s) xp += a * a;
        }
        for (int o = 32; o > 0; o >>= 1) xp += __shfl_down(xp, o);
        if (lane == 0) red4[wv] = xp;
        __syncthreads();
        float xnorm2 = red4[0] + red4[1] + red4[2] + red4[3];
        float alpha = sh.p1.v[s - vbase];
        float beta;
        if (xnorm2 > 0.f) {
          beta  = -copysignf(sqrtf(alpha * alpha + xnorm2), alpha);
          tau   = (beta - alpha) / beta;
          scale = 1.f / (alpha - beta);
        } else { beta = alpha; tau = 0.f; scale = 0.f; }
        if (bid == 0 && tid == 0) {
          p.darr[cloud * NLS + k] = AGLD((float*)&src[k]);
          p.ebuf[cloud * NLS + k] = beta;
        }
        __syncthreads();
        for (int i = tid; i < vn; i += 256) {
          int c = vbase + i;
          sh.p1.v[i] = (c == s) ? 1.f : ((c < s) ? 0.f : sh.p1.v[i] * scale);
        }
        __syncthreads();
      } else {
        float xnorm2 = AGLD(&xn2g[k]);
        float alpha  = AGLD(&acol[s]);
        float beta;
        if (xnorm2 > 0.f) {
          beta  = -copysignf(sqrtf(alpha * alpha + xnorm2), alpha);
          tau   = (beta - alpha) / beta;
          scale = 1.f / (alpha - beta);
        } else { beta = alpha; tau = 0.f; scale = 0.f; }
        if (bid == 0 && tid == 0) {
          p.darr[cloud * NLS + k] = AGLD(&acol[k]);
          p.ebuf[cloud * NLS + k] = beta;
        }
        for (int i = tid; i < vn; i += 256) {
          int c = vbase + i;
          float a = (c < s) ? 0.f : AGLD(&acol[c]);
          sh.p1.v[i] = (c == s) ? 1.f : ((c < s) ? 0.f : a * scale);
        }
        __syncthreads();
      }

      // ---- phase 1: symmetric lower-triangle 64x64 tiles, 2 syncs/tile ----
      const int nwork = T + jj;
      float vtyloc = 0.f;
      for (int item = bid; item < nwork; item += act) {
        if (item < T) {
          const int R0 = R0c, C0 = C0c; const bool dg = dgc;
          __syncthreads();                  // prev tile compute done; safe to overwrite
          {
            const int i0 = tid >> 4, q0 = (tid & 15) << 2;
            float* d0 = &sh.p1.tile[i0][q0];
            d0[0] = rg0.x; d0[1] = rg0.y; d0[2] = rg0.z; d0[3] = rg0.w;
            float* d1 = &sh.p1.tile[i0 + 16][q0];
            d1[0] = rg1.x; d1[1] = rg1.y; d1[2] = rg1.z; d1[3] = rg1.w;
            float* d2 = &sh.p1.tile[i0 + 32][q0];
            d2[0] = rg2.x; d2[1] = rg2.y; d2[2] = rg2.z; d2[3] = rg2.w;
            float* d3 = &sh.p1.tile[i0 + 48][q0];
            d3[0] = rg3.x; d3[1] = rg3.y; d3[2] = rg3.z; d3[3] = rg3.w;
          }
          __syncthreads();                  // tile ready
          int next = item + act;
          if (next < T) { tileIJ(next, R0c, C0c, dgc); loadRegs(R0c, C0c); }
          // per-wave 16-strip partials; direct fire-and-forget atomics to y
          float rp = 0.f, cp = 0.f;
          {
            const float* vrow = &sh.p1.v[C0 - vbase];
            const float* vcol = &sh.p1.v[R0 - vbase];
            const int j0 = wv << 4;
            if (dg) {
              #pragma unroll 4
              for (int j = j0; j < j0 + 16; ++j)
                rp += sh.p1.tile[lane][j] * vrow[j];
            } else {
              #pragma unroll 4
              for (int j = j0; j < j0 + 16; ++j) {
                rp += sh.p1.tile[lane][j] * vrow[j];
                cp += sh.p1.tile[j][lane] * vcol[j];
              }
            }
          }
          if (rp != 0.f) atomicAdd(&yv[R0 + lane], rp);
          vtyloc += rp * sh.p1.v[R0 + lane - vbase];
          if (!dg) {
            if (cp != 0.f) atomicAdd(&yv[C0 + lane], cp);
            vtyloc += cp * sh.p1.v[C0 + lane - vbase];
          }
        } else {
          // c1/c2 dot item: whole WG computes c1[j2], c2[j2] (at most one per WG)
          int j2 = item - T;
          float s1 = 0.f, s2 = 0.f;
          for (int r = s + tid; r < NLS; r += 256) {
            float v = sh.p1.v[r - vbase];
            s1 += Wt[(size_t)j2 * NLS + r] * v;
            s2 += Vt[(size_t)j2 * NLS + r] * v;
          }
          for (int o = 32; o > 0; o >>= 1) {
            s1 += __shfl_down(s1, o);
            s2 += __shfl_down(s2, o);
          }
          if (lane == 0) { rda[wv] = s1; rdb[wv] = s2; }
          __syncthreads();
          if (tid == 0) {
            AGST(&c1g[(size_t)k * NB + j2], rda[0] + rda[1] + rda[2] + rda[3]);
            AGST(&c2g[(size_t)k * NB + j2], rdb[0] + rdb[1] + rdb[2] + rdb[3]);
          }
        }
      }
      // vty: per-wave reduce -> one atomic per WG
      for (int o = 32; o > 0; o >>= 1) vtyloc += __shfl_down(vtyloc, o);
      __syncthreads();
      if (lane == 0) red4[wv] = vtyloc;
      __syncthreads();
      if (tid == 0) {
        float t = red4[0] + red4[1] + red4[2] + red4[3];
        if (t != 0.f) atomicAdd(&p.vtw[cloud * NLS + k], t);
      }

      tbar(bm, act, bid, gen, leafbase, rootbase, false);

      // ---- phase 2: w formation, V/W row jj, next-column acol + xn2, zero ynext ----
      if (tid < jj) {
        c1s[tid] = AGLD(&c1g[(size_t)k * NB + tid]);
        c2s[tid] = AGLD(&c2g[(size_t)k * NB + tid]);
        vks[tid] = Vt[(size_t)tid * NLS + s];
        wks[tid] = Wt[(size_t)tid * NLS + s];
      }
      __syncthreads();
      float vty = AGLD(&p.vtw[cloud * NLS + k]);
      float dotc = 0.f, corrs = 0.f;
      for (int j2 = 0; j2 < jj; ++j2) {
        dotc  += c1s[j2] * c2s[j2];
        corrs += vks[j2] * c1s[j2] + wks[j2] * c2s[j2];
      }
      float s2v = tau * (vty - 2.f * dotc);
      float ys  = AGLD(&yv[s]);
      float wfirst = tau * ys - tau * corrs - 0.5f * tau * s2v;   // v[s] = 1
      bool havenext = (jj < NB - 1);
      const float* Arow = A + (size_t)s * NLS;
      float xpart = 0.f;
      for (int r = s + (bid << 8) + tid; r < NLS; r += (act << 8)) {
        float vr = sh.p1.v[r - vbase];
        float yr = AGLD(&yv[r]);
        float corr = 0.f, ac2 = 0.f;
        for (int j2 = 0; j2 < jj; ++j2) {
          float vj = Vt[(size_t)j2 * NLS + r];
          float wj = Wt[(size_t)j2 * NLS + r];
          corr += vj * c1s[j2] + wj * c2s[j2];
          ac2  += vj * wks[j2] + wj * vks[j2];
        }
        float wr = tau * yr - tau * corr - 0.5f * tau * s2v * vr;
        AGST(&Vt[(size_t)jj * NLS + r], vr);
        AGST(&Wt[(size_t)jj * NLS + r], wr);
        AGST(&ynext[r], 0.f);                     // pre-zero next column's y
        if (havenext) {
          float ac = Arow[r] - ac2 - (vr * wfirst + wr);
          AGST(&acol[r], ac);
          if (r >= s + 2) xpart += ac * ac;       // = xnorm2 of column k+1
        }
      }
      if (havenext) {
        for (int o = 32; o > 0; o >>= 1) xpart += __shfl_down(xpart, o);
        if (lane == 0) red4[wv] = xpart;
        __syncthreads();
        if (tid == 0) {
          float t = red4[0] + red4[1] + red4[2] + red4[3];
          if (t != 0.f) atomicAdd(&xn2g[k + 1], t);
        }
      }

      tbar(bm, act, bid, gen, leafbase, rootbase, false);
    }

    // ---- trailing rank-2*NB update: A -= V W^T + W V^T, 64x64 tiles ----
    {
      const int base2 = k0 + NB;
      const int nt2 = (NLS - base2 + 63) >> 6;
      const int ntt = nt2 * nt2;
      for (int it = bid; it < ntt; it += act) {
        int by = it / nt2, bx = it - by * nt2;
        int r0t = base2 + (by << 6), c0t = base2 + (bx << 6);
        __syncthreads();
        for (int idx = tid; idx < NB * 64; idx += 256) {
          int j4 = idx >> 6, i = idx & 63;
          int r = r0t + i, c = c0t + i;
          sh.t.Vr[j4][i] = (r < NLS) ? Vt[(size_t)j4 * NLS + r] : 0.f;
          sh.t.Wr[j4][i] = (r < NLS) ? Wt[(size_t)j4 * NLS + r] : 0.f;
          sh.t.Vc[j4][i] = (c < NLS) ? Vt[(size_t)j4 * NLS + c] : 0.f;
          sh.t.Wc[j4][i] = (c < NLS) ? Wt[(size_t)j4 * NLS + c] : 0.f;
        }
        __syncthreads();
        int ty = tid >> 4, tx = tid & 15;
        float acc[4][4] = {{0.f}};
        for (int j4 = 0; j4 < NB; ++j4) {
          float vr[4], wr[4], vc[4], wc[4];
          for (int a = 0; a < 4; ++a) {
            vr[a] = sh.t.Vr[j4][ty * 4 + a]; wr[a] = sh.t.Wr[j4][ty * 4 + a];
            vc[a] = sh.t.Vc[j4][tx * 4 + a]; wc[a] = sh.t.Wc[j4][tx * 4 + a];
          }
          for (int a = 0; a < 4; ++a)
            for (int b = 0; b < 4; ++b)
              acc[a][b] += vr[a] * wc[b] + wr[a] * vc[b];
        }
        for (int a = 0; a < 4; ++a) {
          int r = r0t + ty * 4 + a;
          int c = c0t + tx * 4;
          if (r < NLS && c < NLS) {
            float4* pa = (float4*)&A[(size_t)r * NLS + c];
            float4 old = *pa;
            old.x -= acc[a][0]; old.y -= acc[a][1];
            old.z -= acc[a][2]; old.w -= acc[a][3];
            *pa = old;
          }
        }
      }
      tbar(bm, act, bid, gen, leafbase, rootbase, true);
    }
  }
}

// ---------------- trailing 64x64 block: in-LDS tridiagonalization ----------------
__global__ void ktrail_kernel(Ptrs p, int cloud0) {
  int cloud = cloud0 + blockIdx.z;
  float* A = matA(p, cloud);
  const int base = NLS - 64;
  int lane = threadIdx.x;  // 64 threads
  __shared__ float B[64][65];
  __shared__ float vv[64], ww[64];
  for (int r = 0; r < 64; ++r)
    B[r][lane] = A[(size_t)(base + r) * NLS + base + lane];
  __syncthreads();
  for (int kl = 0; kl <= 61; ++kl) {
    float val = (lane >= kl + 2) ? B[kl][lane] : 0.f;
    float part = val * val;
    for (int o = 32; o > 0; o >>= 1) part += __shfl_xor(part, o);
    float xnorm2 = part;
    float alpha = B[kl][kl + 1];
    float beta, tau, scale;
    if (xnorm2 > 0.f) {
      beta  = -copysignf(sqrtf(alpha * alpha + xnorm2), alpha);
      tau   = (beta - alpha) / beta;
      scale = 1.f / (alpha - beta);
    } else { beta = alpha; tau = 0.f; scale = 0.f; }
    if (lane == 0) {
      p.darr[cloud * NLS + base + kl] = B[kl][kl];
      p.ebuf[cloud * NLS + base + kl] = beta;
    }
    vv[lane] = (lane == kl + 1) ? 1.f : ((lane >= kl + 2) ? B[kl][lane] * scale : 0.f);
    __syncthreads();
    float yv = 0.f;
    if (lane >= kl + 1)
      for (int c = kl + 1; c < 64; ++c) yv += B[lane][c] * vv[c];
    float vy = (lane >= kl + 1) ? vv[lane] * yv : 0.f;
    for (int o = 32; o > 0; o >>= 1) vy += __shfl_xor(vy, o);
    float w = tau * yv - 0.5f * tau * (tau * vy) * vv[lane];
    ww[lane] = (lane >= kl + 1) ? w : 0.f;
    __syncthreads();
    if (lane >= kl + 1) {
      float vr = vv[lane], wr = ww[lane];
      for (int c = kl + 1; c < 64; ++c)
        B[lane][c] -= vr * ww[c] + wr * vv[c];
    }
    __syncthreads();
  }
  if (lane == 0) {
    p.darr[cloud * NLS + base + 62] = B[62][62];
    p.darr[cloud * NLS + base + 63] = B[63][63];
    p.ebuf[cloud * NLS + base + 62] = B[63][62];
    p.ebuf[cloud * NLS + base + 63] = 0.f;
  }
}

// ---------------- gather tridiagonal + Gershgorin bounds ----------------
__global__ void gather_kernel(Ptrs p, int cloud0) {
  int cloud = cloud0 + blockIdx.z;
  const int n = NLS;
  int tid = threadIdx.x;   // 1024
  const float* d = p.darr + cloud * NLS;
  float* e2 = p.e2 + cloud * NLS;
  __shared__ float elds[NLS];
  for (int i = tid; i < n; i += 1024) {
    float e = (i < n - 1) ? p.ebuf[cloud * NLS + i] : 0.f;
    e2[i]   = e * e;
    elds[i] = fabsf(e);
  }
  __syncthreads();
  float lo = 3.4e38f, hi = -3.4e38f;
  for (int i = tid; i < n; i += 1024) {
    float rad = elds[i] + (i > 0 ? elds[i - 1] : 0.f);
    lo = fminf(lo, d[i] - rad);
    hi = fmaxf(hi, d[i] + rad);
  }
  __shared__ float rl[16], rh[16];
  int lane = tid & 63, wv = tid >> 6;
  for (int o = 32; o > 0; o >>= 1) {
    lo = fminf(lo, __shfl_down(lo, o));
    hi = fmaxf(hi, __shfl_down(hi, o));
  }
  if (lane == 0) { rl[wv] = lo; rh[wv] = hi; }
  __syncthreads();
  if (tid == 0) {
    for (int t = 1; t < 16; ++t) { lo = fminf(lo, rl[t]); hi = fmaxf(hi, rh[t]); }
    p.bounds[cloud * 2 + 0] = lo - 0.5f;
    p.bounds[cloud * 2 + 1] = hi + 0.5f;
  }
}

// ---------------- bisection ----------------
__global__ void bisect_kernel(Ptrs p, int cloud0) {
  int cloud = cloud0 + blockIdx.z;
  int idx = blockIdx.x * 256 + threadIdx.x;
  const float* d  = p.darr + cloud * NLS;
  const float* e2 = p.e2   + cloud * NLS;
  float lo = p.bounds[cloud * 2 + 0];
  float hi = p.bounds[cloud * 2 + 1];
  const float pivmin = 1e-28f;
  for (int it = 0; it < 34; ++it) {
    float mid = 0.5f * (lo + hi);
    int cnt = 0;
    float qq = d[0] - mid;
    if (fabsf(qq) < pivmin) qq = -pivmin;
    cnt += (qq < 0.f);
    for (int i = 1; i < NLS; ++i) {
      qq = d[i] - mid - e2[i - 1] / qq;
      if (fabsf(qq) < pivmin) qq = -pivmin;
      cnt += (qq < 0.f);
    }
    if (cnt > idx) hi = mid; else lo = mid;
  }
  float ev = 0.5f * (lo + hi);
  p.eigs[cloud * NLS + idx] = ev > 0.f ? ev : 0.f;
}

// ---------------- final ----------------
__global__ void final_kernel(Ptrs p, float* out) {
  __shared__ float lds[64];
  int tid = threadIdx.x;   // 256
  for (int cloud = 0; cloud < 2; ++cloud) {
    float num = 0.f, den = 0.f;
    for (int i = tid; i < NLS; i += 256) {
      float lam = p.eigs[cloud * NLS + i];
      float g = 1.f / (1.f + expf(-(lam - 1e-4f) * 100.f));
      num += lam * g;
      den += g;
    }
    for (int o = 32; o > 0; o >>= 1) {
      num += __shfl_down(num, o);
      den += __shfl_down(den, o);
    }
    if ((tid & 63) == 0) { lds[(tid >> 6) * 2] = num; lds[(tid >> 6) * 2 + 1] = den; }
    __syncthreads();
    if (tid == 0) {
      float N = lds[0] + lds[2] + lds[4] + lds[6];
      float D = lds[1] + lds[3] + lds[5] + lds[7];
      lds[32 + cloud] = N / (D + 1e-12f);
    }
    __syncthreads();
  }
  if (tid == 0) {
    float gp = lds[32], gn = lds[33];
    float trip = gp - gn + 0.5f;
    if (trip < 0.f) trip = 0.f;
    out[0] = trip + 0.1f * gp;
  }
}

extern "C" void kernel_launch(void* const* d_in, const int* in_sizes, int n_in,
                              void* d_out, int out_size, void* d_ws, size_t ws_size,
                              hipStream_t stream) {
  const float* q  = (const float*)d_in[0];
  const float* pe = (const float*)d_in[1];
  const float* ne = (const float*)d_in[2];
  const float* W  = (const float*)d_in[3];

  char* base = (char*)d_ws;
  size_t off = 0;
  auto alloc = [&](size_t nbytes) -> void* {
    off = (off + 255) & ~(size_t)255;
    void* r = base + off;
    off += nbytes;
    return r;
  };

  Ptrs p;
  p.X      = (float*)alloc(sizeof(float) * 2 * NNODE * SDIM);
  p.nn     = (int*)  alloc(sizeof(int)   * 2 * NNODE * KNN_K);
  p.nbr    = (int*)  alloc(sizeof(int)   * 2 * NNODE * MAXNBR);
  p.cnt    = (int*)  alloc(sizeof(int)   * 2 * NNODE);
  p.acol   = (float*)alloc(sizeof(float) * 2 * NLS);
  p.darr   = (float*)alloc(sizeof(float) * 2 * NLS);
  p.ebuf   = (float*)alloc(sizeof(float) * 2 * NLS);
  p.e2     = (float*)alloc(sizeof(float) * 2 * NLS);
  p.bounds = (float*)alloc(sizeof(float) * 4);
  p.eigs   = (float*)alloc(sizeof(float) * 2 * NLS);
  p.Vt     = (float*)alloc(sizeof(float) * 2 * NB * NLS);
  p.Wt     = (float*)alloc(sizeof(float) * 2 * NB * NLS);

  // zero-initialized block (contiguous): y (both parities), vtw, xn2, c1, c2, barmem
  size_t zstart = (off + 255) & ~(size_t)255;
  p.y      = (float*)alloc(sizeof(float) * 2 * 2 * NLS);
  p.vtw    = (float*)alloc(sizeof(float) * 2 * NLS);
  p.xn2    = (float*)alloc(sizeof(float) * 2 * NLS);
  p.c1     = (float*)alloc(sizeof(float) * 2 * NLS * NB);
  p.c2     = (float*)alloc(sizeof(float) * 2 * NLS * NB);
  p.barmem = (int*)  alloc(sizeof(int)   * 2 * 2048);
  size_t zend = off;
  long zcount = (long)((zend - zstart) / 4);

  const size_t Abytes = (size_t)NLS * NLS * sizeof(float);
  p.A0 = (float*)alloc(Abytes);
  size_t offA1 = (off + 255) & ~(size_t)255;
  bool batched = (offA1 + Abytes) <= ws_size;
  p.A1 = batched ? (float*)alloc(Abytes) : p.A0;

  // ---- shared preamble ----
  zero_kernel<<<dim3((int)((zcount + 255) / 256)), 256, 0, stream>>>((float*)(base + zstart), zcount);
  proj_kernel<<<dim3(32), 256, 0, stream>>>(p, q, pe, ne, W);
  knn_kernel<<<dim3(NNODE, 1, 2), 64, 0, stream>>>(p);
  adj_kernel<<<dim3(4), 256, 0, stream>>>(p);

  auto run_cloud = [&](int cloud0, int z) {
    assemble_kernel<<<dim3(NNODE, 1, z), 256, 0, stream>>>(p, cloud0);
    mega_kernel<<<dim3(GMEGA, 1, z), 256, 0, stream>>>(p, cloud0);
    ktrail_kernel<<<dim3(1, 1, z), 64, 0, stream>>>(p, cloud0);
    gather_kernel<<<dim3(1, 1, z), 1024, 0, stream>>>(p, cloud0);
    bisect_kernel<<<dim3(NLS / 256, 1, z), 256, 0, stream>>>(p, cloud0);
  };

  if (batched) {
    run_cloud(0, 2);
  } else {
    run_cloud(0, 1);
    run_cloud(1, 1);
  }

  final_kernel<<<dim3(1), 256, 0, stream>>>(p, (float*)d_out);
}

// Round 14
// 99973.907 us; speedup vs baseline: 1.1095x; 1.1095x over previous
//
#include <hip/hip_runtime.h>
#include <math.h>

#define NLS    4096   // 512 nodes * 8 stalk dims (= 64*64, so 64-tiles tile it exactly)
#define NNODE  512
#define SDIM   8
#define KNN_K  5
#define MAXNBR 128
#define DIN    768
#define NB     32     // panel width
#define GMEGA  448    // WGs per z-slice (896 total <= 1024 capacity @ 4 WG/CU)

#define AGLD(p)    __hip_atomic_load((p), __ATOMIC_RELAXED, __HIP_MEMORY_SCOPE_AGENT)
#define AGST(p, v) __hip_atomic_store((p), (v), __ATOMIC_RELAXED, __HIP_MEMORY_SCOPE_AGENT)

struct Ptrs {
  float* X;      // [2][NNODE][SDIM]
  int*   nn;     // [2][NNODE][KNN_K]
  int*   nbr;    // [2][NNODE][MAXNBR]
  int*   cnt;    // [2][NNODE]
  float* y;      // [2][2][NLS]   y accumulator, double-buffered by column parity (zeroed)
  float* acol;   // [2][NLS]      corrected column k (sc1)
  float* vtw;    // [2][NLS]      v^T y accumulators (zeroed, single-use)
  float* xn2;    // [2][NLS]      next-column xnorm2 accumulators (zeroed, single-use)
  float* darr;   // [2][NLS]
  float* ebuf;   // [2][NLS]
  float* e2;     // [2][NLS]
  float* bounds; // [2][2]
  float* eigs;   // [2][NLS]
  float* Vt;     // [2][NB][NLS]
  float* Wt;     // [2][NB][NLS]
  float* c1;     // [2][NLS][NB]  per-column slots (zeroed, single-use)
  float* c2;     // [2][NLS][NB]
  int*   barmem; // [2][2048]     leaves 0..511, root 512, release 768
  float* A0;
  float* A1;
};

__device__ __forceinline__ float* matA(const Ptrs& p, int cloud) {
  return cloud == 0 ? p.A0 : p.A1;
}

// Two-level tree barrier with generation counting (proven R6-R12).
__device__ __forceinline__ void tbar(int* bm, int act, int bid, int& gen,
                                     int& leafbase, int& rootbase, bool fence) {
  __syncthreads();
  if (threadIdx.x == 0) {
    gen += 1;
    int perleaf = act >> 5;                       // act is a multiple of 32
    if (fence) __threadfence();
    else       __builtin_amdgcn_s_waitcnt(0);
    int* leaf = bm + ((bid & 31) << 4);
    int old = __hip_atomic_fetch_add(leaf, 1, __ATOMIC_RELAXED, __HIP_MEMORY_SCOPE_AGENT);
    if (old == leafbase + perleaf - 1) {
      int ro = __hip_atomic_fetch_add(bm + 512, 1, __ATOMIC_RELAXED, __HIP_MEMORY_SCOPE_AGENT);
      if (ro == rootbase + 31) AGST(bm + 768, gen);
    }
    leafbase += perleaf;
    rootbase += 32;
    while (AGLD(bm + 768) < gen) __builtin_amdgcn_s_sleep(8);
    if (fence) __threadfence();
  }
  __syncthreads();
}

// ---------------- zero helper ----------------
__global__ void zero_kernel(float* ptr, long n) {
  long i = (long)blockIdx.x * 256 + threadIdx.x;
  if (i < n) ptr[i] = 0.f;
}

// ---------------- projection: X = emb @ W^T ----------------
__global__ void proj_kernel(Ptrs p, const float* q, const float* pe,
                            const float* ne, const float* W) {
  int idx = blockIdx.x * 256 + threadIdx.x;
  if (idx >= 2 * NNODE * SDIM) return;
  int cloud = idx >> 12;
  int rem   = idx & 4095;
  int node  = rem >> 3, t = rem & 7;
  const float* src = (node < 256) ? (q + (size_t)node * DIN)
                                  : ((cloud == 0 ? pe : ne) + (size_t)(node - 256) * DIN);
  const float* wr = W + (size_t)t * DIN;
  float acc = 0.f;
  for (int i = 0; i < DIN; ++i) acc += src[i] * wr[i];
  p.X[(cloud * NNODE + node) * SDIM + t] = acc;
}

// ---------------- KNN ----------------
__global__ void knn_kernel(Ptrs p) {
  int i = blockIdx.x, cloud = blockIdx.z;
  int lane = threadIdx.x;
  __shared__ float d2s[NNODE];
  const float* X = p.X + cloud * NNODE * SDIM;
  float xi[SDIM];
  for (int t = 0; t < SDIM; ++t) xi[t] = X[i * SDIM + t];
  for (int j = lane; j < NNODE; j += 64) {
    float s = 0.f;
    for (int t = 0; t < SDIM; ++t) { float d = xi[t] - X[j * SDIM + t]; s += d * d; }
    d2s[j] = (j == i) ? 3.4e38f : s;
  }
  __syncthreads();
  for (int r = 0; r < KNN_K; ++r) {
    float bv = 3.39e38f; int bi = NNODE;
    for (int j = lane; j < NNODE; j += 64) {
      float val = d2s[j];
      if (val < bv || (val == bv && j < bi)) { bv = val; bi = j; }
    }
    for (int o = 32; o > 0; o >>= 1) {
      float ov = __shfl_down(bv, o); int oi = __shfl_down(bi, o);
      if (ov < bv || (ov == bv && oi < bi)) { bv = ov; bi = oi; }
    }
    if (lane == 0) {
      p.nn[(cloud * NNODE + i) * KNN_K + r] = bi;
      d2s[bi] = 3.4e38f;
    }
    __syncthreads();
  }
}

// ---------------- symmetrized adjacency ----------------
__global__ void adj_kernel(Ptrs p) {
  int idx = blockIdx.x * 256 + threadIdx.x;
  if (idx >= 2 * NNODE) return;
  int cloud = idx >> 9, i = idx & 511;
  const int* nn = p.nn + cloud * NNODE * KNN_K;
  int c = 0;
  for (int j = 0; j < NNODE; ++j) {
    if (j == i) continue;
    bool e = false;
    for (int r = 0; r < KNN_K; ++r)
      if (nn[i * KNN_K + r] == j || nn[j * KNN_K + r] == i) e = true;
    if (e) { if (c < MAXNBR) p.nbr[(cloud * NNODE + i) * MAXNBR + c] = j; ++c; }
  }
  p.cnt[cloud * NNODE + i] = (c > MAXNBR ? MAXNBR : c);
}

// ---------------- dense assembly of L (full square) ----------------
__global__ void assemble_kernel(Ptrs p, int cloud0) {
  int i = blockIdx.x;
  int cloud = cloud0 + blockIdx.z;
  float* A = matA(p, cloud);
  const float* X = p.X + cloud * NNODE * SDIM;
  const int* nbr = p.nbr + (cloud * NNODE + i) * MAXNBR;
  int cnt = p.cnt[cloud * NNODE + i];
  int tid = threadIdx.x;

  for (int idx = tid; idx < SDIM * NLS; idx += 256) {
    int t = idx >> 12;
    int c = idx & 4095;
    A[(size_t)(i * SDIM + t) * NLS + c] = 0.f;
  }
  __shared__ float diag[64];
  __shared__ float xi[SDIM];
  if (tid < SDIM) xi[tid] = X[i * SDIM + tid];
  if (tid < 64)   diag[tid] = 0.f;
  __syncthreads();

  for (int s = 0; s < cnt; ++s) {
    int j = nbr[s];
    float d[SDIM], ss = 0.f;
    for (int t = 0; t < SDIM; ++t) { d[t] = X[j * SDIM + t] - xi[t]; ss += d[t] * d[t]; }
    float dn = sqrtf(ss) + 1e-12f;
    float alpha = dn < 1.f ? dn : 1.f;
    float inv = 1.f / dn;
    if (tid < 64) {
      int t = tid >> 3, t2 = tid & 7;
      float ut = d[t] * inv, ut2 = d[t2] * inv;
      A[(size_t)(i * SDIM + t) * NLS + j * SDIM + t2] =
          alpha * ut * ut2 - (t == t2 ? 1.f : 0.f);
      if (j < i) {
        float beta = 2.f * alpha - alpha * alpha;
        diag[tid] += beta * ut * ut2;
      }
    }
  }
  __syncthreads();
  if (tid < 64) {
    int t = tid >> 3, t2 = tid & 7;
    A[(size_t)(i * SDIM + t) * NLS + i * SDIM + t2] =
        (t == t2 ? (float)cnt : 0.f) - diag[tid];
  }
}

// ---------------- persistent mega-kernel: full blocked tridiagonalization ----
// R12 operating point: symmetric tiled GEMV, register-prefetch pipeline,
// staged LDS reduce (atomic-coalescing), 4 WG/CU.
__global__ __launch_bounds__(256, 4) void mega_kernel(Ptrs p, int cloud0) {
  const int cloud = cloud0 + blockIdx.z;
  const int bid = blockIdx.x;
  float* A  = matA(p, cloud);
  float* Vt = p.Vt + (size_t)cloud * NB * NLS;
  float* Wt = p.Wt + (size_t)cloud * NB * NLS;
  float* acol = p.acol + (size_t)cloud * NLS;
  float* c1g = p.c1 + (size_t)cloud * NLS * NB;
  float* c2g = p.c2 + (size_t)cloud * NLS * NB;
  float* xn2g = p.xn2 + (size_t)cloud * NLS;
  int* bm = p.barmem + (size_t)cloud * 2048;
  int gen = 0, leafbase = 0, rootbase = 0;
  const int tid = threadIdx.x, lane = tid & 63, wv = tid >> 6;

  __shared__ __align__(16) union {
    struct {
      float v[NLS + 4];           // 16.4 KB  (live through phase 1+2)
      float tile[64][65];         // 16.6 KB  (per-tile staging, pad 65: conflict-free)
      float rpw[4][64];           // 1 KB
      float cpw[4][64];           // 1 KB
    } p1;
    struct { float Vr[NB][64], Wr[NB][64], Vc[NB][64], Wc[NB][64]; } t;  // 32 KB
  } sh;
  __shared__ float c1s[NB], c2s[NB], vks[NB], wks[NB];
  __shared__ float red4[4];

  for (int k0 = 0; k0 + NB <= NLS - 64; k0 += NB) {
    int act = (NLS - k0) >> 3;
    act = (act + 31) & ~31;
    if (act < 64)    act = 64;
    if (act > GMEGA) act = GMEGA;
    if (bid >= act) return;

    for (int jj = 0; jj < NB; ++jj) {
      const int k = k0 + jj, s = k + 1;
      const int vbase = s & ~63;          // 64-aligned tile/v origin
      const int vn = NLS - vbase;
      float* yv    = p.y + ((size_t)cloud * 2 + (k & 1)) * NLS;
      float* ynext = p.y + ((size_t)cloud * 2 + ((k + 1) & 1)) * NLS;

      // ---- column preamble: Householder scalars + stage v (scaled) ----
      float tau, scale;
      if (jj == 0) {
        const float* src = A + (size_t)k * NLS;   // stale row k
        float xp = 0.f;
        for (int i = tid; i < vn; i += 256) {
          int c = vbase + i;
          float a = (c < s) ? 0.f : AGLD((float*)&src[c]);
          sh.p1.v[i] = a;
          if (c > s) xp += a * a;
        }
        for (int o = 32; o > 0; o >>= 1) xp += __shfl_down(xp, o);
        if (lane == 0) red4[wv] = xp;
        __syncthreads();
        float xnorm2 = red4[0] + red4[1] + red4[2] + red4[3];
        float alpha = sh.p1.v[s - vbase];
        float beta;
        if (xnorm2 > 0.f) {
          beta  = -copysignf(sqrtf(alpha * alpha + xnorm2), alpha);
          tau   = (beta - alpha) / beta;
          scale = 1.f / (alpha - beta);
        } else { beta = alpha; tau = 0.f; scale = 0.f; }
        if (bid == 0 && tid == 0) {
          p.darr[cloud * NLS + k] = AGLD((float*)&src[k]);
          p.ebuf[cloud * NLS + k] = beta;
        }
        __syncthreads();
        for (int i = tid; i < vn; i += 256) {
          int c = vbase + i;
          sh.p1.v[i] = (c == s) ? 1.f : ((c < s) ? 0.f : sh.p1.v[i] * scale);
        }
        __syncthreads();
      } else {
        float xnorm2 = AGLD(&xn2g[k]);
        float alpha  = AGLD(&acol[s]);
        float beta;
        if (xnorm2 > 0.f) {
          beta  = -copysignf(sqrtf(alpha * alpha + xnorm2), alpha);
          tau   = (beta - alpha) / beta;
          scale = 1.f / (alpha - beta);
        } else { beta = alpha; tau = 0.f; scale = 0.f; }
        if (bid == 0 && tid == 0) {
          p.darr[cloud * NLS + k] = AGLD(&acol[k]);
          p.ebuf[cloud * NLS + k] = beta;
        }
        for (int i = tid; i < vn; i += 256) {
          int c = vbase + i;
          float a = (c < s) ? 0.f : AGLD(&acol[c]);
          sh.p1.v[i] = (c == s) ? 1.f : ((c < s) ? 0.f : a * scale);
        }
        __syncthreads();
      }

      // ---- phase 1: symmetric lower-triangle 64x64 tiles (pipelined) + dots ----
      const int nt = vn >> 6;                 // tiles exactly cover [vbase, NLS)
      const int T = (nt * (nt + 1)) >> 1;
      const int nwork = T + jj;
      float vtyloc = 0.f;                     // nonzero only in waves 0/1

      // tile index decode
      auto tileIJ = [&](int item, int& R0, int& C0, bool& dg) {
        int I = (int)((sqrtf(8.f * (float)item + 1.f) - 1.f) * 0.5f);
        while (((I + 1) * (I + 2)) / 2 <= item) ++I;
        while ((I * (I + 1)) / 2 > item) --I;
        int J = item - (I * (I + 1)) / 2;
        R0 = vbase + (I << 6); C0 = vbase + (J << 6); dg = (I == J);
      };
      float4 rg0, rg1, rg2, rg3;
      auto loadRegs = [&](int R0, int C0) {
        const int i0 = tid >> 4, q0 = (tid & 15) << 2;
        const float* basep = A + (size_t)R0 * NLS + C0;
        rg0 = *(const float4*)(basep + (size_t)(i0     ) * NLS + q0);
        rg1 = *(const float4*)(basep + (size_t)(i0 + 16) * NLS + q0);
        rg2 = *(const float4*)(basep + (size_t)(i0 + 32) * NLS + q0);
        rg3 = *(const float4*)(basep + (size_t)(i0 + 48) * NLS + q0);
      };

      int R0c = 0, C0c = 0; bool dgc = false;
      if (bid < T) { tileIJ(bid, R0c, C0c, dgc); loadRegs(R0c, C0c); }

      for (int item = bid; item < nwork; item += act) {
        __syncthreads();                      // tile LDS safe to overwrite
        if (item < T) {
          const int R0 = R0c, C0 = C0c; const bool dg = dgc;
          // write prefetched regs -> LDS tile
          {
            const int i0 = tid >> 4, q0 = (tid & 15) << 2;
            float* d0 = &sh.p1.tile[i0][q0];
            d0[0] = rg0.x; d0[1] = rg0.y; d0[2] = rg0.z; d0[3] = rg0.w;
            float* d1 = &sh.p1.tile[i0 + 16][q0];
            d1[0] = rg1.x; d1[1] = rg1.y; d1[2] = rg1.z; d1[3] = rg1.w;
            float* d2 = &sh.p1.tile[i0 + 32][q0];
            d2[0] = rg2.x; d2[1] = rg2.y; d2[2] = rg2.z; d2[3] = rg2.w;
            float* d3 = &sh.p1.tile[i0 + 48][q0];
            d3[0] = rg3.x; d3[1] = rg3.y; d3[2] = rg3.z; d3[3] = rg3.w;
          }
          __syncthreads();
          // prefetch next tile into regs (overlaps compute below)
          int next = item + act;
          if (next < T) { tileIJ(next, R0c, C0c, dgc); loadRegs(R0c, C0c); }
          // partials: lane = row (rp) / col (cp); wave wv sweeps its 16-strip
          float rp = 0.f, cp = 0.f;
          {
            const float* vrow = &sh.p1.v[C0 - vbase];
            const float* vcol = &sh.p1.v[R0 - vbase];
            const int j0 = wv << 4;
            if (dg) {
              #pragma unroll 4
              for (int j = j0; j < j0 + 16; ++j)
                rp += sh.p1.tile[lane][j] * vrow[j];
            } else {
              #pragma unroll 4
              for (int j = j0; j < j0 + 16; ++j) {
                rp += sh.p1.tile[lane][j] * vrow[j];
                cp += sh.p1.tile[j][lane] * vcol[j];
              }
            }
          }
          sh.p1.rpw[wv][lane] = rp;
          sh.p1.cpw[wv][lane] = cp;
          __syncthreads();
          if (wv == 0) {
            float rsum = sh.p1.rpw[0][lane] + sh.p1.rpw[1][lane]
                       + sh.p1.rpw[2][lane] + sh.p1.rpw[3][lane];
            if (rsum != 0.f) atomicAdd(&yv[R0 + lane], rsum);
            vtyloc += rsum * sh.p1.v[R0 + lane - vbase];
          } else if (wv == 1 && !dg) {
            float csum = sh.p1.cpw[0][lane] + sh.p1.cpw[1][lane]
                       + sh.p1.cpw[2][lane] + sh.p1.cpw[3][lane];
            if (csum != 0.f) atomicAdd(&yv[C0 + lane], csum);
            vtyloc += csum * sh.p1.v[C0 + lane - vbase];
          }
        } else {
          // c1/c2 dot item: whole WG computes c1[j2], c2[j2]
          int j2 = item - T;
          float s1 = 0.f, s2 = 0.f;
          for (int r = s + tid; r < NLS; r += 256) {
            float v = sh.p1.v[r - vbase];
            s1 += Wt[(size_t)j2 * NLS + r] * v;
            s2 += Vt[(size_t)j2 * NLS + r] * v;
          }
          for (int o = 32; o > 0; o >>= 1) {
            s1 += __shfl_down(s1, o);
            s2 += __shfl_down(s2, o);
          }
          if (lane == 0) { sh.p1.rpw[wv][0] = s1; sh.p1.rpw[wv][1] = s2; }
          __syncthreads();
          if (tid == 0) {
            AGST(&c1g[(size_t)k * NB + j2],
                 sh.p1.rpw[0][0] + sh.p1.rpw[1][0] + sh.p1.rpw[2][0] + sh.p1.rpw[3][0]);
            AGST(&c2g[(size_t)k * NB + j2],
                 sh.p1.rpw[0][1] + sh.p1.rpw[1][1] + sh.p1.rpw[2][1] + sh.p1.rpw[3][1]);
          }
        }
      }
      // vty: per-wave reduce -> one atomic per WG
      for (int o = 32; o > 0; o >>= 1) vtyloc += __shfl_down(vtyloc, o);
      __syncthreads();
      if (lane == 0) red4[wv] = vtyloc;
      __syncthreads();
      if (tid == 0) {
        float t = red4[0] + red4[1] + red4[2] + red4[3];
        if (t != 0.f) atomicAdd(&p.vtw[cloud * NLS + k], t);
      }

      tbar(bm, act, bid, gen, leafbase, rootbase, false);

      // ---- phase 2: w formation, V/W row jj, next-column acol + xn2, zero ynext ----
      if (tid < jj) {
        c1s[tid] = AGLD(&c1g[(size_t)k * NB + tid]);
        c2s[tid] = AGLD(&c2g[(size_t)k * NB + tid]);
        vks[tid] = Vt[(size_t)tid * NLS + s];
        wks[tid] = Wt[(size_t)tid * NLS + s];
      }
      __syncthreads();
      float vty = AGLD(&p.vtw[cloud * NLS + k]);
      float dotc = 0.f, corrs = 0.f;
      for (int j2 = 0; j2 < jj; ++j2) {
        dotc  += c1s[j2] * c2s[j2];
        corrs += vks[j2] * c1s[j2] + wks[j2] * c2s[j2];
      }
      float s2v = tau * (vty - 2.f * dotc);
      float* yvp = p.y + ((size_t)cloud * 2 + (k & 1)) * NLS;
      float ys  = AGLD(&yvp[s]);
      float wfirst = tau * ys - tau * corrs - 0.5f * tau * s2v;   // v[s] = 1
      bool havenext = (jj < NB - 1);
      const float* Arow = A + (size_t)s * NLS;
      float xpart = 0.f;
      for (int r = s + (bid << 8) + tid; r < NLS; r += (act << 8)) {
        float vr = sh.p1.v[r - vbase];
        float yr = AGLD(&yvp[r]);
        float corr = 0.f, ac2 = 0.f;
        for (int j2 = 0; j2 < jj; ++j2) {
          float vj = Vt[(size_t)j2 * NLS + r];
          float wj = Wt[(size_t)j2 * NLS + r];
          corr += vj * c1s[j2] + wj * c2s[j2];
          ac2  += vj * wks[j2] + wj * vks[j2];
        }
        float wr = tau * yr - tau * corr - 0.5f * tau * s2v * vr;
        AGST(&Vt[(size_t)jj * NLS + r], vr);
        AGST(&Wt[(size_t)jj * NLS + r], wr);
        AGST(&ynext[r], 0.f);                     // pre-zero next column's y
        if (havenext) {
          float ac = Arow[r] - ac2 - (vr * wfirst + wr);
          AGST(&acol[r], ac);
          if (r >= s + 2) xpart += ac * ac;       // = xnorm2 of column k+1
        }
      }
      if (havenext) {
        for (int o = 32; o > 0; o >>= 1) xpart += __shfl_down(xpart, o);
        if (lane == 0) red4[wv] = xpart;
        __syncthreads();
        if (tid == 0) {
          float t = red4[0] + red4[1] + red4[2] + red4[3];
          if (t != 0.f) atomicAdd(&xn2g[k + 1], t);
        }
      }

      tbar(bm, act, bid, gen, leafbase, rootbase, false);
    }

    // ---- trailing rank-2*NB update: A -= V W^T + W V^T, 64x64 tiles ----
    {
      const int base2 = k0 + NB;
      const int nt2 = (NLS - base2 + 63) >> 6;
      const int ntt = nt2 * nt2;
      for (int it = bid; it < ntt; it += act) {
        int by = it / nt2, bx = it - by * nt2;
        int r0t = base2 + (by << 6), c0t = base2 + (bx << 6);
        __syncthreads();
        for (int idx = tid; idx < NB * 64; idx += 256) {
          int j4 = idx >> 6, i = idx & 63;
          int r = r0t + i, c = c0t + i;
          sh.t.Vr[j4][i] = (r < NLS) ? Vt[(size_t)j4 * NLS + r] : 0.f;
          sh.t.Wr[j4][i] = (r < NLS) ? Wt[(size_t)j4 * NLS + r] : 0.f;
          sh.t.Vc[j4][i] = (c < NLS) ? Vt[(size_t)j4 * NLS + c] : 0.f;
          sh.t.Wc[j4][i] = (c < NLS) ? Wt[(size_t)j4 * NLS + c] : 0.f;
        }
        __syncthreads();
        int ty = tid >> 4, tx = tid & 15;
        float acc[4][4] = {{0.f}};
        for (int j4 = 0; j4 < NB; ++j4) {
          float vr[4], wr[4], vc[4], wc[4];
          for (int a = 0; a < 4; ++a) {
            vr[a] = sh.t.Vr[j4][ty * 4 + a]; wr[a] = sh.t.Wr[j4][ty * 4 + a];
            vc[a] = sh.t.Vc[j4][tx * 4 + a]; wc[a] = sh.t.Wc[j4][tx * 4 + a];
          }
          for (int a = 0; a < 4; ++a)
            for (int b = 0; b < 4; ++b)
              acc[a][b] += vr[a] * wc[b] + wr[a] * vc[b];
        }
        for (int a = 0; a < 4; ++a) {
          int r = r0t + ty * 4 + a;
          int c = c0t + tx * 4;
          if (r < NLS && c < NLS) {
            float4* pa = (float4*)&A[(size_t)r * NLS + c];
            float4 old = *pa;
            old.x -= acc[a][0]; old.y -= acc[a][1];
            old.z -= acc[a][2]; old.w -= acc[a][3];
            *pa = old;
          }
        }
      }
      tbar(bm, act, bid, gen, leafbase, rootbase, true);
    }
  }
}

// ---------------- trailing 64x64 block: in-LDS tridiagonalization ----------------
__global__ void ktrail_kernel(Ptrs p, int cloud0) {
  int cloud = cloud0 + blockIdx.z;
  float* A = matA(p, cloud);
  const int base = NLS - 64;
  int lane = threadIdx.x;  // 64 threads
  __shared__ float B[64][65];
  __shared__ float vv[64], ww[64];
  for (int r = 0; r < 64; ++r)
    B[r][lane] = A[(size_t)(base + r) * NLS + base + lane];
  __syncthreads();
  for (int kl = 0; kl <= 61; ++kl) {
    float val = (lane >= kl + 2) ? B[kl][lane] : 0.f;
    float part = val * val;
    for (int o = 32; o > 0; o >>= 1) part += __shfl_xor(part, o);
    float xnorm2 = part;
    float alpha = B[kl][kl + 1];
    float beta, tau, scale;
    if (xnorm2 > 0.f) {
      beta  = -copysignf(sqrtf(alpha * alpha + xnorm2), alpha);
      tau   = (beta - alpha) / beta;
      scale = 1.f / (alpha - beta);
    } else { beta = alpha; tau = 0.f; scale = 0.f; }
    if (lane == 0) {
      p.darr[cloud * NLS + base + kl] = B[kl][kl];
      p.ebuf[cloud * NLS + base + kl] = beta;
    }
    vv[lane] = (lane == kl + 1) ? 1.f : ((lane >= kl + 2) ? B[kl][lane] * scale : 0.f);
    __syncthreads();
    float yv = 0.f;
    if (lane >= kl + 1)
      for (int c = kl + 1; c < 64; ++c) yv += B[lane][c] * vv[c];
    float vy = (lane >= kl + 1) ? vv[lane] * yv : 0.f;
    for (int o = 32; o > 0; o >>= 1) vy += __shfl_xor(vy, o);
    float w = tau * yv - 0.5f * tau * (tau * vy) * vv[lane];
    ww[lane] = (lane >= kl + 1) ? w : 0.f;
    __syncthreads();
    if (lane >= kl + 1) {
      float vr = vv[lane], wr = ww[lane];
      for (int c = kl + 1; c < 64; ++c)
        B[lane][c] -= vr * ww[c] + wr * vv[c];
    }
    __syncthreads();
  }
  if (lane == 0) {
    p.darr[cloud * NLS + base + 62] = B[62][62];
    p.darr[cloud * NLS + base + 63] = B[63][63];
    p.ebuf[cloud * NLS + base + 62] = B[63][62];
    p.ebuf[cloud * NLS + base + 63] = 0.f;
  }
}

// ---------------- gather tridiagonal + Gershgorin bounds ----------------
__global__ void gather_kernel(Ptrs p, int cloud0) {
  int cloud = cloud0 + blockIdx.z;
  const int n = NLS;
  int tid = threadIdx.x;   // 1024
  const float* d = p.darr + cloud * NLS;
  float* e2 = p.e2 + cloud * NLS;
  __shared__ float elds[NLS];
  for (int i = tid; i < n; i += 1024) {
    float e = (i < n - 1) ? p.ebuf[cloud * NLS + i] : 0.f;
    e2[i]   = e * e;
    elds[i] = fabsf(e);
  }
  __syncthreads();
  float lo = 3.4e38f, hi = -3.4e38f;
  for (int i = tid; i < n; i += 1024) {
    float rad = elds[i] + (i > 0 ? elds[i - 1] : 0.f);
    lo = fminf(lo, d[i] - rad);
    hi = fmaxf(hi, d[i] + rad);
  }
  __shared__ float rl[16], rh[16];
  int lane = tid & 63, wv = tid >> 6;
  for (int o = 32; o > 0; o >>= 1) {
    lo = fminf(lo, __shfl_down(lo, o));
    hi = fmaxf(hi, __shfl_down(hi, o));
  }
  if (lane == 0) { rl[wv] = lo; rh[wv] = hi; }
  __syncthreads();
  if (tid == 0) {
    for (int t = 1; t < 16; ++t) { lo = fminf(lo, rl[t]); hi = fmaxf(hi, rh[t]); }
    p.bounds[cloud * 2 + 0] = lo - 0.5f;
    p.bounds[cloud * 2 + 1] = hi + 0.5f;
  }
}

// ---------------- bisection ----------------
__global__ void bisect_kernel(Ptrs p, int cloud0) {
  int cloud = cloud0 + blockIdx.z;
  int idx = blockIdx.x * 256 + threadIdx.x;
  const float* d  = p.darr + cloud * NLS;
  const float* e2 = p.e2   + cloud * NLS;
  float lo = p.bounds[cloud * 2 + 0];
  float hi = p.bounds[cloud * 2 + 1];
  const float pivmin = 1e-28f;
  for (int it = 0; it < 34; ++it) {
    float mid = 0.5f * (lo + hi);
    int cnt = 0;
    float qq = d[0] - mid;
    if (fabsf(qq) < pivmin) qq = -pivmin;
    cnt += (qq < 0.f);
    for (int i = 1; i < NLS; ++i) {
      qq = d[i] - mid - e2[i - 1] / qq;
      if (fabsf(qq) < pivmin) qq = -pivmin;
      cnt += (qq < 0.f);
    }
    if (cnt > idx) hi = mid; else lo = mid;
  }
  float ev = 0.5f * (lo + hi);
  p.eigs[cloud * NLS + idx] = ev > 0.f ? ev : 0.f;
}

// ---------------- final ----------------
__global__ void final_kernel(Ptrs p, float* out) {
  __shared__ float lds[64];
  int tid = threadIdx.x;   // 256
  for (int cloud = 0; cloud < 2; ++cloud) {
    float num = 0.f, den = 0.f;
    for (int i = tid; i < NLS; i += 256) {
      float lam = p.eigs[cloud * NLS + i];
      float g = 1.f / (1.f + expf(-(lam - 1e-4f) * 100.f));
      num += lam * g;
      den += g;
    }
    for (int o = 32; o > 0; o >>= 1) {
      num += __shfl_down(num, o);
      den += __shfl_down(den, o);
    }
    if ((tid & 63) == 0) { lds[(tid >> 6) * 2] = num; lds[(tid >> 6) * 2 + 1] = den; }
    __syncthreads();
    if (tid == 0) {
      float N = lds[0] + lds[2] + lds[4] + lds[6];
      float D = lds[1] + lds[3] + lds[5] + lds[7];
      lds[32 + cloud] = N / (D + 1e-12f);
    }
    __syncthreads();
  }
  if (tid == 0) {
    float gp = lds[32], gn = lds[33];
    float trip = gp - gn + 0.5f;
    if (trip < 0.f) trip = 0.f;
    out[0] = trip + 0.1f * gp;
  }
}

extern "C" void kernel_launch(void* const* d_in, const int* in_sizes, int n_in,
                              void* d_out, int out_size, void* d_ws, size_t ws_size,
                              hipStream_t stream) {
  const float* q  = (const float*)d_in[0];
  const float* pe = (const float*)d_in[1];
  const float* ne = (const float*)d_in[2];
  const float* W  = (const float*)d_in[3];

  char* base = (char*)d_ws;
  size_t off = 0;
  auto alloc = [&](size_t nbytes) -> void* {
    off = (off + 255) & ~(size_t)255;
    void* r = base + off;
    off += nbytes;
    return r;
  };

  Ptrs p;
  p.X      = (float*)alloc(sizeof(float) * 2 * NNODE * SDIM);
  p.nn     = (int*)  alloc(sizeof(int)   * 2 * NNODE * KNN_K);
  p.nbr    = (int*)  alloc(sizeof(int)   * 2 * NNODE * MAXNBR);
  p.cnt    = (int*)  alloc(sizeof(int)   * 2 * NNODE);
  p.acol   = (float*)alloc(sizeof(float) * 2 * NLS);
  p.darr   = (float*)alloc(sizeof(float) * 2 * NLS);
  p.ebuf   = (float*)alloc(sizeof(float) * 2 * NLS);
  p.e2     = (float*)alloc(sizeof(float) * 2 * NLS);
  p.bounds = (float*)alloc(sizeof(float) * 4);
  p.eigs   = (float*)alloc(sizeof(float) * 2 * NLS);
  p.Vt     = (float*)alloc(sizeof(float) * 2 * NB * NLS);
  p.Wt     = (float*)alloc(sizeof(float) * 2 * NB * NLS);

  // zero-initialized block (contiguous): y (both parities), vtw, xn2, c1, c2, barmem
  size_t zstart = (off + 255) & ~(size_t)255;
  p.y      = (float*)alloc(sizeof(float) * 2 * 2 * NLS);
  p.vtw    = (float*)alloc(sizeof(float) * 2 * NLS);
  p.xn2    = (float*)alloc(sizeof(float) * 2 * NLS);
  p.c1     = (float*)alloc(sizeof(float) * 2 * NLS * NB);
  p.c2     = (float*)alloc(sizeof(float) * 2 * NLS * NB);
  p.barmem = (int*)  alloc(sizeof(int)   * 2 * 2048);
  size_t zend = off;
  long zcount = (long)((zend - zstart) / 4);

  const size_t Abytes = (size_t)NLS * NLS * sizeof(float);
  p.A0 = (float*)alloc(Abytes);
  size_t offA1 = (off + 255) & ~(size_t)255;
  bool batched = (offA1 + Abytes) <= ws_size;
  p.A1 = batched ? (float*)alloc(Abytes) : p.A0;

  // ---- shared preamble ----
  zero_kernel<<<dim3((int)((zcount + 255) / 256)), 256, 0, stream>>>((float*)(base + zstart), zcount);
  proj_kernel<<<dim3(32), 256, 0, stream>>>(p, q, pe, ne, W);
  knn_kernel<<<dim3(NNODE, 1, 2), 64, 0, stream>>>(p);
  adj_kernel<<<dim3(4), 256, 0, stream>>>(p);

  auto run_cloud = [&](int cloud0, int z) {
    assemble_kernel<<<dim3(NNODE, 1, z), 256, 0, stream>>>(p, cloud0);
    mega_kernel<<<dim3(GMEGA, 1, z), 256, 0, stream>>>(p, cloud0);
    ktrail_kernel<<<dim3(1, 1, z), 64, 0, stream>>>(p, cloud0);
    gather_kernel<<<dim3(1, 1, z), 1024, 0, stream>>>(p, cloud0);
    bisect_kernel<<<dim3(NLS / 256, 1, z), 256, 0, stream>>>(p, cloud0);
  };

  if (batched) {
    run_cloud(0, 2);
  } else {
    run_cloud(0, 1);
    run_cloud(1, 1);
  }

  final_kernel<<<dim3(1), 256, 0, stream>>>(p, (float*)d_out);
}